// Round 1
// baseline (528.298 us; speedup 1.0000x reference)
//
#include <hip/hip_runtime.h>

// Asymmetric EMA over T, x: [B=16, T=4096, C=1024] fp32.
// y[0] = x[0]; y[t] = a*y[t-1] + (1-a)*x[t], a = (y[t-1] > x[t]) ? 0.99 : 0.5
// Rewritten as y = x + a*(y_prev - x).
// One thread per (b,c) sequence: lane-consecutive c -> coalesced at each t.
// 64-thread blocks, 256 blocks -> 1 wave on each of 256 CUs.
// Unroll U=16, prefetch distance 2 (two register groups in flight) for MLP.

constexpr int B = 16;
constexpr int T = 4096;
constexpr int C = 1024;
constexpr float ALPHA_FALL = 0.99f;
constexpr float ALPHA_RISE = 0.5f;
constexpr int U = 16;                 // steps per group
constexpr int G = (T - 1) / U;        // 255 full groups covering t=1..4080

__global__ __launch_bounds__(64) void AsymmetricEMA_kernel(
    const float* __restrict__ x, float* __restrict__ out) {
  const int tid = blockIdx.x * 64 + threadIdx.x;      // 0..16383
  const int b = tid >> 10;                            // / C
  const int c = tid & (C - 1);                        // % C
  const size_t base = (size_t)b * (size_t)T * (size_t)C + (size_t)c;

  const float* __restrict__ xp = x + base;
  float* __restrict__ op = out + base;

  // t = 0: pass-through
  float y = xp[0];
  op[0] = y;

  float b0[U], b1[U];

  auto loadgrp = [&](float* buf, int g) {
    const float* p = xp + (size_t)(1 + g * U) * (size_t)C;
#pragma unroll
    for (int j = 0; j < U; ++j) buf[j] = p[(size_t)j * (size_t)C];
  };
  auto compute_store = [&](const float* buf, int g) {
    float* p = op + (size_t)(1 + g * U) * (size_t)C;
#pragma unroll
    for (int j = 0; j < U; ++j) {
      const float xv = buf[j];
      const float d = y - xv;
      const float a = (d > 0.0f) ? ALPHA_FALL : ALPHA_RISE;
      y = __builtin_fmaf(a, d, xv);
      p[(size_t)j * (size_t)C] = y;
    }
  };

  loadgrp(b0, 0);
  loadgrp(b1, 1);
  int g = 0;
  while (true) {
    compute_store(b0, g);
    if (g + 2 < G) loadgrp(b0, g + 2);
    ++g;
    if (g >= G) break;
    compute_store(b1, g);
    if (g + 2 < G) loadgrp(b1, g + 2);
    ++g;
    if (g >= G) break;
  }

  // tail: t = 1 + G*U .. T-1  (15 steps)
  for (int t = 1 + G * U; t < T; ++t) {
    const float xv = xp[(size_t)t * (size_t)C];
    const float d = y - xv;
    const float a = (d > 0.0f) ? ALPHA_FALL : ALPHA_RISE;
    y = __builtin_fmaf(a, d, xv);
    op[(size_t)t * (size_t)C] = y;
  }
}

extern "C" void kernel_launch(void* const* d_in, const int* in_sizes, int n_in,
                              void* d_out, int out_size, void* d_ws, size_t ws_size,
                              hipStream_t stream) {
  const float* x = (const float*)d_in[0];
  float* out = (float*)d_out;
  const int threads = B * C;          // 16384
  AsymmetricEMA_kernel<<<threads / 64, 64, 0, stream>>>(x, out);
}

// Round 2
// 439.346 us; speedup vs baseline: 1.2025x; 1.2025x over previous
//
#include <hip/hip_runtime.h>

// Asymmetric EMA over T, x: [B=16, T=4096, C=1024] fp32.
// y[0] = x[0]; y[t] = a*y[t-1] + (1-a)*x[t], a = (y[t-1] > x[t]) ? 0.99 : 0.5
// Rewritten: y = x + a*(y_prev - x)  (slope <= 0.99 -> contraction).
//
// R2: latency-bound fix.
//  - U=32 unroll, prefetch distance 2 -> up to 64 outstanding loads/wave.
//  - T split into 2 chunks; chunk 1 warm-starts 1025 steps early (error
//    decays by 0.99^1024 ~ 3.4e-5, way under the 0.08 threshold).
//    -> 512 waves = 2 waves/CU so compute overlaps another wave's latency.

constexpr int B = 16;
constexpr int T = 4096;
constexpr int C = 1024;
constexpr float ALPHA_FALL = 0.99f;
constexpr float ALPHA_RISE = 0.5f;
constexpr int U = 32;           // steps per group
constexpr int NSEQ = B * C;     // 16384 independent sequences
constexpr int TSPLIT = 2048;    // chunk-1 store range [2048, 4096)
constexpr int WARM = 1025;      // warm-up window (start t = 1023)

__device__ inline float ema_step(float y, float xv) {
  const float d = y - xv;
  const float a = (d > 0.0f) ? ALPHA_FALL : ALPHA_RISE;
  return __builtin_fmaf(a, d, xv);
}

// Process t in [t_from, t_to), groups of U, prefetch distance 2.
template <bool STORE>
__device__ inline void run_steps(const float* __restrict__ xp,
                                 float* __restrict__ op, float& y,
                                 int t_from, int t_to) {
  const int n = t_to - t_from;
  const int ngrp = n / U;
  const float* p = xp + (size_t)t_from * (size_t)C;
  float* q = op + (size_t)t_from * (size_t)C;

  float b0[U], b1[U];
  auto load = [&](float* buf, int g) {
    const float* pp = p + (size_t)g * (size_t)U * (size_t)C;
#pragma unroll
    for (int j = 0; j < U; ++j) buf[j] = pp[(size_t)j * (size_t)C];
  };
  auto comp = [&](const float* buf, int g) {
    float* qq = q + (size_t)g * (size_t)U * (size_t)C;
#pragma unroll
    for (int j = 0; j < U; ++j) {
      y = ema_step(y, buf[j]);
      if (STORE) qq[(size_t)j * (size_t)C] = y;
    }
  };

  if (ngrp >= 1) load(b0, 0);
  if (ngrp >= 2) load(b1, 1);
  int g = 0;
  while (g < ngrp) {
    comp(b0, g);
    if (g + 2 < ngrp) load(b0, g + 2);
    ++g;
    if (g >= ngrp) break;
    comp(b1, g);
    if (g + 2 < ngrp) load(b1, g + 2);
    ++g;
  }

  // Remainder (< U steps): issue all loads first, then the serial chain.
  const int r = n - ngrp * U;
  if (r > 0) {
    float br[U];
    const float* pp = p + (size_t)ngrp * (size_t)U * (size_t)C;
    float* qq = q + (size_t)ngrp * (size_t)U * (size_t)C;
#pragma unroll
    for (int j = 0; j < U; ++j)
      if (j < r) br[j] = pp[(size_t)j * (size_t)C];
#pragma unroll
    for (int j = 0; j < U; ++j)
      if (j < r) {
        y = ema_step(y, br[j]);
        if (STORE) qq[(size_t)j * (size_t)C] = y;
      }
  }
}

__global__ __launch_bounds__(64) void AsymmetricEMA_kernel(
    const float* __restrict__ x, float* __restrict__ out) {
  const int tid = blockIdx.x * 64 + threadIdx.x;  // 0..16383
  const int b = tid >> 10;                        // / C
  const int c = tid & (C - 1);                    // % C
  const size_t base = (size_t)b * (size_t)T * (size_t)C + (size_t)c;
  const float* __restrict__ xp = x + base;
  float* __restrict__ op = out + base;

  if (blockIdx.y == 0) {
    // chunk 0: exact. t=0 pass-through, then steps 1..2047, stored.
    float y = xp[0];
    op[0] = y;
    run_steps<true>(xp, op, y, 1, TSPLIT);
  } else {
    // chunk 1: warm-start at t = TSPLIT - WARM with y = x (pass-through),
    // run WARM-1 un-stored steps, then store [TSPLIT, T).
    const int s0 = TSPLIT - WARM;  // 1023
    float y = xp[(size_t)s0 * (size_t)C];
    run_steps<false>(xp, op, y, s0 + 1, TSPLIT);
    run_steps<true>(xp, op, y, TSPLIT, T);
  }
}

extern "C" void kernel_launch(void* const* d_in, const int* in_sizes, int n_in,
                              void* d_out, int out_size, void* d_ws, size_t ws_size,
                              hipStream_t stream) {
  const float* x = (const float*)d_in[0];
  float* out = (float*)d_out;
  dim3 grid(NSEQ / 64, 2);  // (256 blocks per chunk) x 2 chunks
  AsymmetricEMA_kernel<<<grid, 64, 0, stream>>>(x, out);
}